// Round 5
// baseline (1080.935 us; speedup 1.0000x reference)
//
#include <hip/hip_runtime.h>
#include <hip/hip_bf16.h>

typedef __bf16 bf16;
typedef __bf16 bf16x4 __attribute__((ext_vector_type(4)));
typedef __bf16 bf16x8 __attribute__((ext_vector_type(8)));
typedef float f32x4 __attribute__((ext_vector_type(4)));

#define GLD16(gp, sp) __builtin_amdgcn_global_load_lds( \
    (const __attribute__((address_space(1))) void*)(gp), \
    (__attribute__((address_space(3))) void*)(sp), 16, 0, 0)

constexpr int UNITS = 8;
constexpr int BATCH = 65536;
constexpr int DIM   = 256;    // I == H == 256
constexpr int BM = 128;       // rows per block
constexpr int BN = 32;        // H-columns per block
constexpr int BK = 32;        // K-chunk => 28KB LDS => 4 blocks/CU
constexpr int NW = 4;         // waves per block

constexpr size_t XN = (size_t)BATCH * DIM;            // 16,777,216
constexpr size_t WN = (size_t)UNITS * 3 * DIM * DIM;  // 1,572,864

__device__ __forceinline__ float sigmoidf_fast(float x) {
    return 1.0f / (1.0f + __expf(-x));
}
__device__ __forceinline__ float tanhf_fast(float x) {
    float y = fminf(fmaxf(x, -15.0f), 15.0f);
    float e = __expf(-2.0f * y);
    return (1.0f - e) / (1.0f + e);
}

__global__ void convert_kernel(const float* __restrict__ x,
                               const float* __restrict__ Wih,
                               const float* __restrict__ Whh,
                               const float* __restrict__ h0,
                               bf16* __restrict__ xbf,
                               bf16* __restrict__ Wihbf,
                               bf16* __restrict__ Whhbf,
                               bf16* __restrict__ h0bf)
{
    const size_t total4 = (XN + 2 * WN + DIM) / 4;
    size_t i4 = (size_t)blockIdx.x * blockDim.x + threadIdx.x;
    if (i4 >= total4) return;
    size_t e = i4 * 4;
    const float* src; bf16* dst; size_t off;
    if (e < XN)               { src = x;   dst = xbf;   off = e; }
    else if (e < XN + WN)     { src = Wih; dst = Wihbf; off = e - XN; }
    else if (e < XN + 2 * WN) { src = Whh; dst = Whhbf; off = e - XN - WN; }
    else                      { src = h0;  dst = h0bf;  off = e - XN - 2 * WN; }
    const float4 v = *(const float4*)(src + off);
    bf16x4 o;
    o[0] = (bf16)v.x; o[1] = (bf16)v.y; o[2] = (bf16)v.z; o[3] = (bf16)v.w;
    *(bf16x4*)(dst + off) = o;
}

// LDS swizzle: logical 16B k-slot s of row r lives at physical slot
// s ^ ((r>>1)&3). Fragment ds_read_b128 then hits all 8 bank groups per
// 8 consecutive lanes (paper-check: groups {0,4,1,5,2,6,3,7}) — conflict-free.
// K-loop iterates kc = (jidx+1+t)&7 so the LAST staged chunk is kc==jidx:
// hs then holds h columns j0..j0+31 and the epilogue reads h from LDS.
__global__ __launch_bounds__(256, 4)
void gru_unit_kernel(const bf16* __restrict__ x,       // [B,256] bf16
                     const bf16* __restrict__ h_prev,  // [B,256] bf16 (or h0, stride 0)
                     long h_row_stride,
                     const bf16* __restrict__ Wih,     // [768,256] bf16 unit slice
                     const bf16* __restrict__ Whh,     // [768,256] bf16
                     const float* __restrict__ bih,    // [768] f32
                     const float* __restrict__ bhh,    // [768] f32
                     bf16* __restrict__ out_bf,        // bf16 intermediate or null
                     float* __restrict__ out_f32)      // f32 final or null
{
    __shared__ __align__(16) bf16 xs[BM * BK];      // 8 KB
    __shared__ __align__(16) bf16 hs[BM * BK];      // 8 KB
    __shared__ __align__(16) bf16 wi[3 * BN * BK];  // 6 KB
    __shared__ __align__(16) bf16 wh[3 * BN * BK];  // 6 KB => 28 KB

    const int tid  = threadIdx.x;
    const int wave = tid >> 6;
    const int lane = tid & 63;
    const int quad = lane >> 4;
    const int l15  = lane & 15;

    // 1-D grid: consecutive blocks = 8 j-tiles of the SAME m-tile, landing on
    // XCDs 0..7 simultaneously -> x/h tile: 1 HBM fetch + L3 broadcast.
    const int b    = blockIdx.x;
    const int jidx = b & 7;
    const int j0   = jidx * BN;
    const int m0   = (b >> 3) * BM;

    // Staging: chunk = 1KB = 16 rows x 32 cols. Lane l writes LDS +l*16B
    // (row l>>2, physical slot l&3) => fetch logical slot (l&3)^((l>>3)&3).
    const int srow = lane >> 2;
    const int scol = ((lane & 3) ^ ((lane >> 3) & 3)) * 8;

    // Hoisted per-chunk global pointers (k0=0) + wave-uniform LDS dsts.
    const bf16* gsrc[7];
    bf16* ldst[7];
#pragma unroll
    for (int i = 0; i < 7; ++i) {
        const int c = wave + i * NW;   // 0..27, each exactly once
        if (c < 8) {
            const int row = c * 16 + srow;
            gsrc[i] = x + (size_t)(m0 + row) * DIM + scol;
            ldst[i] = xs + c * 512;
        } else if (c < 16) {
            const int row = (c - 8) * 16 + srow;
            gsrc[i] = h_prev + (size_t)(m0 + row) * h_row_stride + scol;
            ldst[i] = hs + (c - 8) * 512;
        } else if (c < 22) {
            const int lr = (c - 16) * 16 + srow;        // 0..95
            const int grow = (lr >> 5) * DIM + j0 + (lr & 31);
            gsrc[i] = Wih + (size_t)grow * DIM + scol;
            ldst[i] = wi + (c - 16) * 512;
        } else {
            const int lr = (c - 22) * 16 + srow;
            const int grow = (lr >> 5) * DIM + j0 + (lr & 31);
            gsrc[i] = Whh + (size_t)grow * DIM + scol;
            ldst[i] = wh + (c - 22) * 512;
        }
    }

    // Hoisted fragment LDS element-offsets (kc-invariant).
    int a_off[2], b_off[3][2];
#pragma unroll
    for (int mt = 0; mt < 2; ++mt) {
        const int r = wave * 32 + mt * 16 + l15;
        a_off[mt] = r * BK + (quad ^ ((r >> 1) & 3)) * 8;
    }
#pragma unroll
    for (int g = 0; g < 3; ++g)
#pragma unroll
        for (int hh = 0; hh < 2; ++hh) {
            const int r = g * BN + hh * 16 + l15;
            b_off[g][hh] = r * BK + (quad ^ ((r >> 1) & 3)) * 8;
        }

    f32x4 acc[4][2][2];   // [r,z,ni,nh][mt][tn]
#pragma unroll
    for (int g = 0; g < 4; ++g)
#pragma unroll
        for (int mt = 0; mt < 2; ++mt)
#pragma unroll
            for (int tn = 0; tn < 2; ++tn)
                acc[g][mt][tn] = (f32x4){0.f, 0.f, 0.f, 0.f};

#pragma unroll
    for (int t = 0; t < 8; ++t) {
        const int kc = (jidx + 1 + t) & 7;
        const int k0 = kc * BK;
        __syncthreads();   // LDS free to overwrite
#pragma unroll
        for (int i = 0; i < 7; ++i)
            GLD16(gsrc[i] + k0, ldst[i]);
        __syncthreads();   // staging visible

        bf16x8 ax[2], ah[2];
#pragma unroll
        for (int mt = 0; mt < 2; ++mt) {
            ax[mt] = *(const bf16x8*)(xs + a_off[mt]);
            ah[mt] = *(const bf16x8*)(hs + a_off[mt]);
        }
#pragma unroll
        for (int g = 0; g < 3; ++g) {
            const bf16x8 bi0 = *(const bf16x8*)(wi + b_off[g][0]);
            const bf16x8 bi1 = *(const bf16x8*)(wi + b_off[g][1]);
            const bf16x8 bh0 = *(const bf16x8*)(wh + b_off[g][0]);
            const bf16x8 bh1 = *(const bf16x8*)(wh + b_off[g][1]);
            if (g < 2) {   // r, z: merged x/h accumulation
#pragma unroll
                for (int mt = 0; mt < 2; ++mt) {
                    acc[g][mt][0] = __builtin_amdgcn_mfma_f32_16x16x32_bf16(ax[mt], bi0, acc[g][mt][0], 0, 0, 0);
                    acc[g][mt][1] = __builtin_amdgcn_mfma_f32_16x16x32_bf16(ax[mt], bi1, acc[g][mt][1], 0, 0, 0);
                    acc[g][mt][0] = __builtin_amdgcn_mfma_f32_16x16x32_bf16(ah[mt], bh0, acc[g][mt][0], 0, 0, 0);
                    acc[g][mt][1] = __builtin_amdgcn_mfma_f32_16x16x32_bf16(ah[mt], bh1, acc[g][mt][1], 0, 0, 0);
                }
            } else {       // n: split accumulators
#pragma unroll
                for (int mt = 0; mt < 2; ++mt) {
                    acc[2][mt][0] = __builtin_amdgcn_mfma_f32_16x16x32_bf16(ax[mt], bi0, acc[2][mt][0], 0, 0, 0);
                    acc[2][mt][1] = __builtin_amdgcn_mfma_f32_16x16x32_bf16(ax[mt], bi1, acc[2][mt][1], 0, 0, 0);
                    acc[3][mt][0] = __builtin_amdgcn_mfma_f32_16x16x32_bf16(ah[mt], bh0, acc[3][mt][0], 0, 0, 0);
                    acc[3][mt][1] = __builtin_amdgcn_mfma_f32_16x16x32_bf16(ah[mt], bh1, acc[3][mt][1], 0, 0, 0);
                }
            }
        }
    }
    // no barrier needed: hs last written at t=7 (kc==jidx), already barriered.

    // Epilogue: C/D layout col = lane&15, row = quad*4 + reg.
#pragma unroll
    for (int tn = 0; tn < 2; ++tn) {
        const int jc = j0 + tn * 16 + l15;
        const float br  = bih[jc]           + bhh[jc];
        const float bz  = bih[DIM + jc]     + bhh[DIM + jc];
        const float bni = bih[2 * DIM + jc];
        const float bnh = bhh[2 * DIM + jc];
        const int cl = tn * 16 + l15;          // column within hs chunk
        const int s  = cl >> 3;                // logical 16B slot
#pragma unroll
        for (int mt = 0; mt < 2; ++mt) {
            const int row0 = m0 + wave * 32 + mt * 16 + quad * 4;
            const int rl0  = wave * 32 + mt * 16 + quad * 4;
#pragma unroll
            for (int i = 0; i < 4; ++i) {
                const size_t idx = (size_t)(row0 + i) * DIM + jc;
                const int rl = rl0 + i;
                const float hp = (float)hs[rl * BK + (s ^ ((rl >> 1) & 3)) * 8 + (cl & 7)];
                const float r = sigmoidf_fast(acc[0][mt][tn][i] + br);
                const float z = sigmoidf_fast(acc[1][mt][tn][i] + bz);
                const float n = tanhf_fast(acc[2][mt][tn][i] + bni
                                           + r * (acc[3][mt][tn][i] + bnh));
                const float hv = n + z * (hp - n);
                if (out_f32) out_f32[idx] = hv;
                else         out_bf[idx] = (bf16)hv;
            }
        }
    }
}

extern "C" void kernel_launch(void* const* d_in, const int* in_sizes, int n_in,
                              void* d_out, int out_size, void* d_ws, size_t ws_size,
                              hipStream_t stream) {
    const float* x   = (const float*)d_in[0];
    const float* Wih = (const float*)d_in[1];
    const float* Whh = (const float*)d_in[2];
    const float* bih = (const float*)d_in[3];
    const float* bhh = (const float*)d_in[4];
    const float* h0  = (const float*)d_in[5];
    float* out = (float*)d_out;

    bf16* xbf   = (bf16*)d_ws;
    bf16* Wihbf = xbf + XN;
    bf16* Whhbf = Wihbf + WN;
    bf16* h0bf  = Whhbf + WN;
    bf16* hA    = h0bf + 256;              // ws total ~74 MB
    bf16* hB    = (bf16*)d_out;            // unit 7 reads hA, overwrites d_out f32

    {
        const size_t total4 = (XN + 2 * WN + DIM) / 4;
        const int cblocks = (int)((total4 + 255) / 256);
        hipLaunchKernelGGL(convert_kernel, dim3(cblocks), dim3(256), 0, stream,
                           x, Wih, Whh, h0, xbf, Wihbf, Whhbf, h0bf);
    }

    dim3 grid((BATCH / BM) * (DIM / BN));   // 4096, j = b&7, m = b>>3
    dim3 block(256);

    for (int u = 0; u < UNITS; ++u) {
        const bf16* hp; long hstride;
        if (u == 0)      { hp = h0bf; hstride = 0; }
        else if (u & 1)  { hp = hA;   hstride = DIM; }
        else             { hp = hB;   hstride = DIM; }
        bf16* ob = nullptr; float* of = nullptr;
        if (u == UNITS - 1) of = out;
        else ob = (u & 1) ? hB : hA;
        hipLaunchKernelGGL(gru_unit_kernel, grid, block, 0, stream,
                           xbf, hp, hstride,
                           Wihbf + (size_t)u * 3 * DIM * DIM,
                           Whhbf + (size_t)u * 3 * DIM * DIM,
                           bih + (size_t)u * 3 * DIM,
                           bhh + (size_t)u * 3 * DIM,
                           ob, of);
    }
}